// Round 5
// baseline (303.364 us; speedup 1.0000x reference)
//
#include <hip/hip_runtime.h>
#include <hip/hip_bf16.h>

#define BSZ 4
#define SEQ 512
#define HID 768
#define VOC 30522
#define NPAD 30592   // 239*128

typedef __attribute__((ext_vector_type(8))) short short8;
typedef __attribute__((ext_vector_type(4))) float f32x4;

typedef const unsigned int __attribute__((address_space(1)))* gptr_t;
typedef unsigned int __attribute__((address_space(3)))* lptr_t;

__device__ __forceinline__ void gload_lds16(const void* g, void* l) {
    __builtin_amdgcn_global_load_lds((gptr_t)g, (lptr_t)l, 16, 0, 0);
}

// ---------------- span scans: fw = cummax, bw = reverse cummin ----------------
__global__ __launch_bounds__(512) void scan_kernel(const int* __restrict__ span,
                                                   int* __restrict__ fw, int* __restrict__ bw) {
    int b = blockIdx.x;
    int j = threadIdx.x;   // 0..511
    __shared__ int sm[SEQ];
    __shared__ int sc[SEQ];
    int m = (span[b * SEQ + j] > -1) ? 1 : 0;
    sm[j] = m;
    __syncthreads();
    int prev = (j > 0) ? sm[j - 1] : 0;
    int nxt  = (j < SEQ - 1) ? sm[j + 1] : 0;
    int cfw = (m && !prev && j > 0) ? (j - 1) : 0;
    int cbw = (m && !nxt && j < SEQ - 1) ? (j + 1) : (SEQ - 1);

    int v = cfw;
    sc[j] = v; __syncthreads();
    for (int off = 1; off < SEQ; off <<= 1) {
        int o = (j >= off) ? sc[j - off] : 0;
        __syncthreads();
        v = max(v, o);
        sc[j] = v; __syncthreads();
    }
    fw[b * SEQ + j] = v;

    v = cbw;
    sc[j] = v; __syncthreads();
    for (int off = 1; off < SEQ; off <<= 1) {
        int o = (j + off < SEQ) ? sc[j + off] : (SEQ - 1);
        __syncthreads();
        v = min(v, o);
        sc[j] = v; __syncthreads();
    }
    bw[b * SEQ + j] = v;
}

// ---------------- build X = [fw_h | bw_h | pe] * mask, bf16 ----------------
__global__ __launch_bounds__(256) void build_x(const float* __restrict__ h,
                                               const int* __restrict__ span,
                                               const float* __restrict__ pe,
                                               const int* __restrict__ fw,
                                               const int* __restrict__ bw,
                                               __hip_bfloat16* __restrict__ X) {
    int r = blockIdx.x;            // 0..2047
    int b = r >> 9, s = r & (SEQ - 1);
    float mf = (span[r] > -1) ? 1.f : 0.f;
    int f = fw[r], w = bw[r];
    const float* hf = h + ((size_t)b * SEQ + f) * HID;
    const float* hb = h + ((size_t)b * SEQ + w) * HID;
    const float* pp = pe + (size_t)s * HID;
    __hip_bfloat16* xr = X + (size_t)r * (3 * HID);
    for (int c = threadIdx.x; c < HID; c += 256) {
        xr[c]            = __float2bfloat16(hf[c] * mf);
        xr[HID + c]      = __float2bfloat16(hb[c] * mf);
        xr[2 * HID + c]  = __float2bfloat16(pp[c] * mf);
    }
}

// ---------------- transpose + f32->bf16: Wt[n][k] = W[k][n], 64x64 tile ----------------
__global__ __launch_bounds__(256) void transpose64(const float* __restrict__ W,
                                                   __hip_bfloat16* __restrict__ Wt,
                                                   int K, int N) {
    __shared__ float t[64][67];
    int n0 = blockIdx.x * 64, k0 = blockIdx.y * 64;
    int tx = threadIdx.x & 31, ty = threadIdx.x >> 5;  // 32 x 8
    #pragma unroll
    for (int i = 0; i < 64; i += 8) {
        #pragma unroll
        for (int jx = 0; jx < 64; jx += 32) {
            int k = k0 + ty + i, n = n0 + tx + jx;
            t[ty + i][tx + jx] = (n < N) ? W[(size_t)k * N + n] : 0.f;
        }
    }
    __syncthreads();
    #pragma unroll
    for (int i = 0; i < 8; i++) {
        int nn = ty + i * 8;                 // 0..63
        int n = n0 + nn;
        float a = t[tx * 2][nn], b = t[tx * 2 + 1][nn];
        __hip_bfloat16 ba = __float2bfloat16(a), bb = __float2bfloat16(b);
        unsigned int pk = ((unsigned int)*(unsigned short*)&bb << 16) | *(unsigned short*)&ba;
        *(unsigned int*)&Wt[(size_t)n * K + k0 + tx * 2] = pk;
    }
}

// ---------------- bias + exact gelu + layernorm -> bf16 ----------------
__global__ __launch_bounds__(256) void gelu_ln(const float* __restrict__ Y,
                                               const float* __restrict__ bias,
                                               const float* __restrict__ g,
                                               const float* __restrict__ be,
                                               __hip_bfloat16* __restrict__ out) {
    int r = blockIdx.x;
    const float* y = Y + (size_t)r * HID;
    float z[3];
    float s1 = 0.f, s2 = 0.f;
    #pragma unroll
    for (int i = 0; i < 3; i++) {
        int c = threadIdx.x + i * 256;
        float x = y[c] + bias[c];
        float zz = 0.5f * x * (1.f + erff(x * 0.70710678118654752f));
        z[i] = zz; s1 += zz; s2 += zz * zz;
    }
    #pragma unroll
    for (int off = 32; off; off >>= 1) {
        s1 += __shfl_down(s1, off);
        s2 += __shfl_down(s2, off);
    }
    __shared__ float p1[4], p2[4];
    int w = threadIdx.x >> 6, lane = threadIdx.x & 63;
    if (lane == 0) { p1[w] = s1; p2[w] = s2; }
    __syncthreads();
    s1 = p1[0] + p1[1] + p1[2] + p1[3];
    s2 = p2[0] + p2[1] + p2[2] + p2[3];
    float mu = s1 * (1.f / HID);
    float var = s2 * (1.f / HID) - mu * mu;
    float rs = rsqrtf(var + 1e-12f);
    __hip_bfloat16* o = out + (size_t)r * HID;
    #pragma unroll
    for (int i = 0; i < 3; i++) {
        int c = threadIdx.x + i * 256;
        o[c] = __float2bfloat16((z[i] - mu) * rs * g[c] + be[c]);
    }
}

// ---------------- 128x128 MFMA GEMM (kept for the small GEMMs) ----------------
template<bool BIAS_EDGE>
__global__ __launch_bounds__(256) void gemm_kernel(const __hip_bfloat16* __restrict__ A,
                                                   const __hip_bfloat16* __restrict__ Bt,
                                                   float* __restrict__ C,
                                                   int K, int Nvalid,
                                                   const float* __restrict__ bias, int ldc) {
    __shared__ __hip_bfloat16 As[128 * 64];
    __shared__ __hip_bfloat16 Bs[128 * 64];
    int bx = blockIdx.x;
    int by = blockIdx.y;
    int t = threadIdx.x;
    int lane = t & 63, w = t >> 6;
    int wm = w >> 1, wn = w & 1;

    const __hip_bfloat16* Ab = A + (size_t)(by * 128) * K;
    const __hip_bfloat16* Bb = Bt + (size_t)(bx * 128) * K;

    f32x4 acc[4][4] = {};

    for (int k0 = 0; k0 < K; k0 += 64) {
        #pragma unroll
        for (int i = 0; i < 4; i++) {
            int c = i * 256 + t;
            int row = c >> 3, col = (c & 7) * 8;
            gload_lds16(Ab + (size_t)row * K + k0 + col, (char*)As + c * 16);
            gload_lds16(Bb + (size_t)row * K + k0 + col, (char*)Bs + c * 16);
        }
        __syncthreads();
        #pragma unroll
        for (int kk = 0; kk < 64; kk += 32) {
            short8 a[4], b[4];
            int col = kk + (lane >> 4) * 8;
            #pragma unroll
            for (int mi = 0; mi < 4; mi++) {
                int row = wm * 64 + mi * 16 + (lane & 15);
                a[mi] = *(const short8*)&As[row * 64 + col];
            }
            #pragma unroll
            for (int ni = 0; ni < 4; ni++) {
                int row = wn * 64 + ni * 16 + (lane & 15);
                b[ni] = *(const short8*)&Bs[row * 64 + col];
            }
            #pragma unroll
            for (int mi = 0; mi < 4; mi++)
                #pragma unroll
                for (int ni = 0; ni < 4; ni++)
                    acc[mi][ni] = __builtin_amdgcn_mfma_f32_16x16x32_bf16(a[mi], b[ni], acc[mi][ni], 0, 0, 0);
        }
        __syncthreads();
    }

    int rq = lane >> 4, cl = lane & 15;
    #pragma unroll
    for (int mi = 0; mi < 4; mi++) {
        #pragma unroll
        for (int ni = 0; ni < 4; ni++) {
            int col = bx * 128 + wn * 64 + ni * 16 + cl;
            #pragma unroll
            for (int j = 0; j < 4; j++) {
                int row = by * 128 + wm * 64 + mi * 16 + rq * 4 + j;
                float v = acc[mi][ni][j];
                if (BIAS_EDGE) {
                    if (col < Nvalid) C[(size_t)row * ldc + col] = v + bias[col];
                } else {
                    C[(size_t)row * ldc + col] = v;
                }
            }
        }
    }
}

// ---------------- decoder GEMM: 128x128, BK=32, 3-buffer ring, 3 blocks/CU ----------------
// 256 threads = 4 waves (2x2), wave tile 64x64 (acc = 16 f32x4 = 64 VGPR).
// LDS: 3 bufs x 16 KiB: buf r at r*16384; A [128 rows][32k] at +0, B at +8192. Row = 64 B.
// XOR swizzle: byte ^= ((row>>1)&3)<<4  -> uniform 2-way bank aliasing (free), 16B-granular
// so inverse-swizzled global SOURCE + linear gload_lds dest + swizzled ds_read (rule 21).
// Ring: compute buf t%3, stage tile t+2 -> buf (t+2)%3 (4 gload/thread), vmcnt(4) confirms
// tile t+1 while keeping t+2's 4 loads in flight (counted, never 0 in steady state).
// 3 blocks/CU (LDS 48K, VGPR<=168 via launch_bounds(256,3)) -> cross-block latency hiding.
template<bool BIAS_EDGE>
__global__ __launch_bounds__(256, 3) void gemm128(const __hip_bfloat16* __restrict__ A,
                                                  const __hip_bfloat16* __restrict__ Bt,
                                                  float* __restrict__ C,
                                                  int K, int Nvalid,
                                                  const float* __restrict__ bias,
                                                  int ldc, int mtiles) {
    __shared__ char lds[3 * 16384];
    int G = gridDim.x;
    int h = blockIdx.x;
    int chunk = G >> 3;                     // G % 8 == 0
    int l = (h & 7) * chunk + (h >> 3);     // XCD-chunked: each XCD owns a contiguous range
    int bm = l % mtiles;                    // bm fastest: B-panel shared within one XCD
    int bn = l / mtiles;

    int tid = threadIdx.x;
    int lane = tid & 63;
    int w = tid >> 6;            // 0..3
    int wr = w >> 1, wc = w & 1; // 2x2 waves, wave tile 64x64

    // --- staging precompute: thread stages 4 x 16B chunks: A row r0, A r0+64, B r0, B r0+64
    int r0 = tid >> 2;                               // 0..63
    int sc = (tid & 3) ^ ((tid >> 3) & 3);           // inverse-swizzled 16B slot
    const __hip_bfloat16* Abase = A + (size_t)(bm * 128) * K + r0 * K + sc * 8;
    const __hip_bfloat16* Bbase = Bt + (size_t)(bn * 128) * K + r0 * K + sc * 8;
    int ldsw = tid * 16;   // dest within each 4 KiB quarter

    // --- frag read precompute (swizzled)
    int cb = (lane >> 4) * 16;                       // k-octet byte offset
    int ar = wr * 64 + (lane & 15);
    int br = wc * 64 + (lane & 15);
    int aaddr = ar * 64 + (cb ^ (((ar >> 1) & 3) << 4));          // + mi*1024
    int baddr = 8192 + br * 64 + (cb ^ (((br >> 1) & 3) << 4));   // + ni*1024

    f32x4 acc[4][4] = {};
    int nt = K >> 5;   // BK=32

#define STAGE(buf, kt) do { \
        const __hip_bfloat16* ga = Abase + (size_t)(kt) * 32; \
        const __hip_bfloat16* gb = Bbase + (size_t)(kt) * 32; \
        char* dd = lds + (buf) * 16384 + ldsw; \
        gload_lds16(ga,                    dd); \
        gload_lds16(ga + (size_t)64 * K,   dd + 4096); \
        gload_lds16(gb,                    dd + 8192); \
        gload_lds16(gb + (size_t)64 * K,   dd + 12288); } while (0)

    // ---- prologue: tiles 0,1 -> bufs 0,1; confirm tile 0 (keep tile 1 in flight)
    STAGE(0, 0);
    if (nt > 1) STAGE(1, 1);
    asm volatile("s_waitcnt vmcnt(4)" ::: "memory");
    __builtin_amdgcn_s_barrier();

    for (int t = 0; t < nt; ++t) {
        const char* buf = lds + (t % 3) * 16384;
        short8 af[4], bf[4];
        #pragma unroll
        for (int mi = 0; mi < 4; mi++)
            af[mi] = *(const short8*)(buf + aaddr + mi * 1024);
        #pragma unroll
        for (int ni = 0; ni < 4; ni++)
            bf[ni] = *(const short8*)(buf + baddr + ni * 1024);

        if (t + 2 < nt) {
            STAGE((t + 2) % 3, t + 2);
            asm volatile("s_waitcnt vmcnt(4)" ::: "memory");   // confirm tile t+1
        } else if (t + 2 == nt) {
            asm volatile("s_waitcnt vmcnt(0)" ::: "memory");   // confirm last tile
        }
        __builtin_amdgcn_s_barrier();

        __builtin_amdgcn_s_setprio(1);
        #pragma unroll
        for (int mi = 0; mi < 4; mi++)
            #pragma unroll
            for (int ni = 0; ni < 4; ni++)
                acc[mi][ni] = __builtin_amdgcn_mfma_f32_16x16x32_bf16(af[mi], bf[ni], acc[mi][ni], 0, 0, 0);
        __builtin_amdgcn_s_setprio(0);
        __builtin_amdgcn_s_barrier();
    }

    // ---- epilogue
    int rq = lane >> 4, cl = lane & 15;
    #pragma unroll
    for (int mi = 0; mi < 4; mi++) {
        #pragma unroll
        for (int ni = 0; ni < 4; ni++) {
            int col = bn * 128 + wc * 64 + ni * 16 + cl;
            if (!BIAS_EDGE || col < Nvalid) {
                float bv = BIAS_EDGE ? bias[col] : 0.f;
                #pragma unroll
                for (int j = 0; j < 4; j++) {
                    int row = bm * 128 + wr * 64 + mi * 16 + rq * 4 + j;
                    C[(size_t)row * ldc + col] = acc[mi][ni][j] + bv;
                }
            }
        }
    }
#undef STAGE
}

extern "C" void kernel_launch(void* const* d_in, const int* in_sizes, int n_in,
                              void* d_out, int out_size, void* d_ws, size_t ws_size,
                              hipStream_t stream) {
    const float* hidden = (const float*)d_in[0];
    const int*   span   = (const int*)d_in[1];
    const float* pe     = (const float*)d_in[2];
    const float* W1     = (const float*)d_in[3];
    const float* b1     = (const float*)d_in[4];
    const float* g1     = (const float*)d_in[5];
    const float* be1    = (const float*)d_in[6];
    const float* W2     = (const float*)d_in[7];
    const float* b2     = (const float*)d_in[8];
    const float* g2     = (const float*)d_in[9];
    const float* be2    = (const float*)d_in[10];
    const float* Wdec   = (const float*)d_in[11];
    const float* dbias  = (const float*)d_in[12];
    float* out = (float*)d_out;

    const int M = BSZ * SEQ;  // 2048
    char* ws = (char*)d_ws;
    size_t off = 0;
    int* fw = (int*)(ws + off);                 off += (size_t)M * 4;
    int* bw = (int*)(ws + off);                 off += (size_t)M * 4;
    __hip_bfloat16* Xb   = (__hip_bfloat16*)(ws + off); off += (size_t)M * 3 * HID * 2;
    __hip_bfloat16* W1t  = (__hip_bfloat16*)(ws + off); off += (size_t)HID * 3 * HID * 2;
    __hip_bfloat16* W2t  = (__hip_bfloat16*)(ws + off); off += (size_t)HID * HID * 2;
    __hip_bfloat16* Wdt  = (__hip_bfloat16*)(ws + off); off += (size_t)NPAD * HID * 2;
    float* Y             = (float*)(ws + off);          off += (size_t)M * HID * 4;
    __hip_bfloat16* mid  = (__hip_bfloat16*)(ws + off); off += (size_t)M * HID * 2;
    __hip_bfloat16* pre  = (__hip_bfloat16*)(ws + off); off += (size_t)M * HID * 2;

    // 1. span scans
    scan_kernel<<<BSZ, SEQ, 0, stream>>>(span, fw, bw);
    // 2. gather + mask -> X bf16
    build_x<<<M, 256, 0, stream>>>(hidden, span, pe, fw, bw, Xb);
    // 3. weight transposes (f32 -> bf16, B^T layout)
    transpose64<<<dim3(HID / 64, 3 * HID / 64), 256, 0, stream>>>(W1, W1t, 3 * HID, HID);
    transpose64<<<dim3(HID / 64, HID / 64), 256, 0, stream>>>(W2, W2t, HID, HID);
    transpose64<<<dim3(NPAD / 64, HID / 64), 256, 0, stream>>>(Wdec, Wdt, HID, VOC);
    // 4. GEMM1: X[2048,2304] @ W1 -> Y[2048,768]
    gemm_kernel<false><<<dim3(HID / 128, M / 128), 256, 0, stream>>>(Xb, W1t, Y, 3 * HID, 0, nullptr, HID);
    // 5. bias+gelu+LN -> mid bf16
    gelu_ln<<<M, 256, 0, stream>>>(Y, b1, g1, be1, mid);
    // 6. GEMM2: mid @ W2 -> Y
    gemm_kernel<false><<<dim3(HID / 128, M / 128), 256, 0, stream>>>(mid, W2t, Y, HID, 0, nullptr, HID);
    // 7. bias+gelu+LN -> pre bf16
    gelu_ln<<<M, 256, 0, stream>>>(Y, b2, g2, be2, pre);
    // 8. decoder GEMM: 128x128 BK=32 ring, 3 blocks/CU; grid 16*239 = 3824 (8*478)
    gemm128<true><<<(M / 128) * (NPAD / 128), 256, 0, stream>>>(pre, Wdt, out, HID, VOC, dbias, VOC, M / 128);
}

// Round 6
// 252.959 us; speedup vs baseline: 1.1993x; 1.1993x over previous
//
#include <hip/hip_runtime.h>
#include <hip/hip_bf16.h>

#define BSZ 4
#define SEQ 512
#define HID 768
#define VOC 30522
#define NPAD 30720   // 120*256

typedef __attribute__((ext_vector_type(8))) short short8;
typedef __attribute__((ext_vector_type(4))) float f32x4;

typedef const unsigned int __attribute__((address_space(1)))* gptr_t;
typedef unsigned int __attribute__((address_space(3)))* lptr_t;

__device__ __forceinline__ void gload_lds16(const void* g, void* l) {
    __builtin_amdgcn_global_load_lds((gptr_t)g, (lptr_t)l, 16, 0, 0);
}

// ---------------- span scans ----------------
__global__ __launch_bounds__(512) void scan_kernel(const int* __restrict__ span,
                                                   int* __restrict__ fw, int* __restrict__ bw) {
    int b = blockIdx.x;
    int j = threadIdx.x;
    __shared__ int sm[SEQ];
    __shared__ int sc[SEQ];
    int m = (span[b * SEQ + j] > -1) ? 1 : 0;
    sm[j] = m;
    __syncthreads();
    int prev = (j > 0) ? sm[j - 1] : 0;
    int nxt  = (j < SEQ - 1) ? sm[j + 1] : 0;
    int cfw = (m && !prev && j > 0) ? (j - 1) : 0;
    int cbw = (m && !nxt && j < SEQ - 1) ? (j + 1) : (SEQ - 1);

    int v = cfw;
    sc[j] = v; __syncthreads();
    for (int off = 1; off < SEQ; off <<= 1) {
        int o = (j >= off) ? sc[j - off] : 0;
        __syncthreads();
        v = max(v, o);
        sc[j] = v; __syncthreads();
    }
    fw[b * SEQ + j] = v;

    v = cbw;
    sc[j] = v; __syncthreads();
    for (int off = 1; off < SEQ; off <<= 1) {
        int o = (j + off < SEQ) ? sc[j + off] : (SEQ - 1);
        __syncthreads();
        v = min(v, o);
        sc[j] = v; __syncthreads();
    }
    bw[b * SEQ + j] = v;
}

// ---------------- build X = [fw_h | bw_h | pe] * mask, bf16 ----------------
__global__ __launch_bounds__(256) void build_x(const float* __restrict__ h,
                                               const int* __restrict__ span,
                                               const float* __restrict__ pe,
                                               const int* __restrict__ fw,
                                               const int* __restrict__ bw,
                                               __hip_bfloat16* __restrict__ X) {
    int r = blockIdx.x;
    int b = r >> 9, s = r & (SEQ - 1);
    float mf = (span[r] > -1) ? 1.f : 0.f;
    int f = fw[r], w = bw[r];
    const float* hf = h + ((size_t)b * SEQ + f) * HID;
    const float* hb = h + ((size_t)b * SEQ + w) * HID;
    const float* pp = pe + (size_t)s * HID;
    __hip_bfloat16* xr = X + (size_t)r * (3 * HID);
    for (int c = threadIdx.x; c < HID; c += 256) {
        xr[c]            = __float2bfloat16(hf[c] * mf);
        xr[HID + c]      = __float2bfloat16(hb[c] * mf);
        xr[2 * HID + c]  = __float2bfloat16(pp[c] * mf);
    }
}

// ---------------- transpose + f32->bf16, 64x64 tile ----------------
__global__ __launch_bounds__(256) void transpose64(const float* __restrict__ W,
                                                   __hip_bfloat16* __restrict__ Wt,
                                                   int K, int N) {
    __shared__ float t[64][67];
    int n0 = blockIdx.x * 64, k0 = blockIdx.y * 64;
    int tx = threadIdx.x & 31, ty = threadIdx.x >> 5;
    #pragma unroll
    for (int i = 0; i < 64; i += 8) {
        #pragma unroll
        for (int jx = 0; jx < 64; jx += 32) {
            int k = k0 + ty + i, n = n0 + tx + jx;
            t[ty + i][tx + jx] = (n < N) ? W[(size_t)k * N + n] : 0.f;
        }
    }
    __syncthreads();
    #pragma unroll
    for (int i = 0; i < 8; i++) {
        int nn = ty + i * 8;
        int n = n0 + nn;
        float a = t[tx * 2][nn], b = t[tx * 2 + 1][nn];
        __hip_bfloat16 ba = __float2bfloat16(a), bb = __float2bfloat16(b);
        unsigned int pk = ((unsigned int)*(unsigned short*)&bb << 16) | *(unsigned short*)&ba;
        *(unsigned int*)&Wt[(size_t)n * K + k0 + tx * 2] = pk;
    }
}

// ---------------- (y1+y2)+bias, exact gelu, layernorm -> bf16 ----------------
__global__ __launch_bounds__(256) void gelu_ln(const float* __restrict__ Y1,
                                               const float* __restrict__ Y2,
                                               const float* __restrict__ bias,
                                               const float* __restrict__ g,
                                               const float* __restrict__ be,
                                               __hip_bfloat16* __restrict__ out) {
    int r = blockIdx.x;
    const float* y1 = Y1 + (size_t)r * HID;
    const float* y2 = Y2 + (size_t)r * HID;
    float z[3];
    float s1 = 0.f, s2 = 0.f;
    #pragma unroll
    for (int i = 0; i < 3; i++) {
        int c = threadIdx.x + i * 256;
        float x = y1[c] + y2[c] + bias[c];
        float zz = 0.5f * x * (1.f + erff(x * 0.70710678118654752f));
        z[i] = zz; s1 += zz; s2 += zz * zz;
    }
    #pragma unroll
    for (int off = 32; off; off >>= 1) {
        s1 += __shfl_down(s1, off);
        s2 += __shfl_down(s2, off);
    }
    __shared__ float p1[4], p2[4];
    int w = threadIdx.x >> 6, lane = threadIdx.x & 63;
    if (lane == 0) { p1[w] = s1; p2[w] = s2; }
    __syncthreads();
    s1 = p1[0] + p1[1] + p1[2] + p1[3];
    s2 = p2[0] + p2[1] + p2[2] + p2[3];
    float mu = s1 * (1.f / HID);
    float var = s2 * (1.f / HID) - mu * mu;
    float rs = rsqrtf(var + 1e-12f);
    __hip_bfloat16* o = out + (size_t)r * HID;
    #pragma unroll
    for (int i = 0; i < 3; i++) {
        int c = threadIdx.x + i * 256;
        o[c] = __float2bfloat16((z[i] - mu) * rs * g[c] + be[c]);
    }
}

// ---------------- 128x128 MFMA GEMM with blockIdx.z split-K ----------------
// Partial C (no bias) stored to C + z*cstride; summed downstream in gelu_ln.
__global__ __launch_bounds__(256) void gemm_splitk(const __hip_bfloat16* __restrict__ A,
                                                   const __hip_bfloat16* __restrict__ Bt,
                                                   float* __restrict__ C,
                                                   int lda, int Klen, int ldc, size_t cstride) {
    __shared__ __hip_bfloat16 As[128 * 64];
    __shared__ __hip_bfloat16 Bs[128 * 64];
    int bx = blockIdx.x;
    int by = blockIdx.y;
    int koff = blockIdx.z * Klen;
    float* Cz = C + (size_t)blockIdx.z * cstride;
    int t = threadIdx.x;
    int lane = t & 63, w = t >> 6;
    int wm = w >> 1, wn = w & 1;

    const __hip_bfloat16* Ab = A + (size_t)(by * 128) * lda + koff;
    const __hip_bfloat16* Bb = Bt + (size_t)(bx * 128) * lda + koff;

    f32x4 acc[4][4] = {};

    for (int k0 = 0; k0 < Klen; k0 += 64) {
        #pragma unroll
        for (int i = 0; i < 4; i++) {
            int c = i * 256 + t;
            int row = c >> 3, col = (c & 7) * 8;
            gload_lds16(Ab + (size_t)row * lda + k0 + col, (char*)As + c * 16);
            gload_lds16(Bb + (size_t)row * lda + k0 + col, (char*)Bs + c * 16);
        }
        __syncthreads();
        #pragma unroll
        for (int kk = 0; kk < 64; kk += 32) {
            short8 a[4], b[4];
            int col = kk + (lane >> 4) * 8;
            #pragma unroll
            for (int mi = 0; mi < 4; mi++) {
                int row = wm * 64 + mi * 16 + (lane & 15);
                a[mi] = *(const short8*)&As[row * 64 + col];
            }
            #pragma unroll
            for (int ni = 0; ni < 4; ni++) {
                int row = wn * 64 + ni * 16 + (lane & 15);
                b[ni] = *(const short8*)&Bs[row * 64 + col];
            }
            #pragma unroll
            for (int mi = 0; mi < 4; mi++)
                #pragma unroll
                for (int ni = 0; ni < 4; ni++)
                    acc[mi][ni] = __builtin_amdgcn_mfma_f32_16x16x32_bf16(a[mi], b[ni], acc[mi][ni], 0, 0, 0);
        }
        __syncthreads();
    }

    int rq = lane >> 4, cl = lane & 15;
    #pragma unroll
    for (int mi = 0; mi < 4; mi++) {
        #pragma unroll
        for (int ni = 0; ni < 4; ni++) {
            int col = bx * 128 + wn * 64 + ni * 16 + cl;
            #pragma unroll
            for (int j = 0; j < 4; j++) {
                int row = by * 128 + wm * 64 + mi * 16 + rq * 4 + j;
                Cz[(size_t)row * ldc + col] = acc[mi][ni][j];
            }
        }
    }
}

// ---------------- persistent 256x256 8-phase decoder GEMM ----------------
// Grid 240 = 8 XCD x 30. Block handles 4 output tiles sharing one bn (B L2-reuse).
// Tiles: l = (h&7)*30 + (h>>3); bn = l>>1; bm(i) = (l&1)*4 + i, i=0..3.
// 48 virtual K-tiles; ring/vmcnt ledger crosses tile boundaries (one fill/drain per 4 tiles).
// C-write split per-quadrant into the 4 phases of each tile's last K-tile (kk==11),
// so stores drain under the next tile's MFMA. Bias hoisted to regs (cols const/block).
#define KTILES 12
#define TPB 4
#define VTOT (KTILES * TPB)
__global__ __launch_bounds__(512, 2) void gemm256p(const __hip_bfloat16* __restrict__ A,
                                                   const __hip_bfloat16* __restrict__ Bt,
                                                   float* __restrict__ C,
                                                   int K, int Nvalid,
                                                   const float* __restrict__ bias, int ldc) {
    __shared__ char lds[131072];
    int h = blockIdx.x;
    int chunk = gridDim.x >> 3;               // 30
    int l = (h & 7) * chunk + (h >> 3);
    int bn = l >> 1;
    int bm0 = (l & 1) * 4;

    int tid = threadIdx.x;
    int lane = tid & 63;
    int w = tid >> 6;
    int wr = w >> 2, wc = w & 3;

    // staging precompute
    int r0 = tid >> 3;
    int swz8 = (((tid & 7) ^ (r0 & 7)) << 3);
    const __hip_bfloat16* Bbase = Bt + (size_t)(bn * 256) * K;
    size_t arow0 = (size_t)r0 * K + swz8;
    size_t arow1 = arow0 + (size_t)64 * K;
    int ldsw = tid * 16;

    // frag read precompute (swizzled)
    int rxor = (lane & 7) << 4;
    int rcol = ((lane >> 4) & 3) * 16;
    int rc0 = (0 + rcol) ^ rxor;
    int rc1 = (64 + rcol) ^ rxor;
    int aoff = (wr * 64 + (lane & 15)) * 128;
    int boff = 32768 + (wc * 32 + (lane & 15)) * 128;

    // hoist bias: col depends on (qn,ni) only
    int rq = lane >> 4, cl = lane & 15;
    float bv[2][2];
    #pragma unroll
    for (int qn = 0; qn < 2; qn++)
        #pragma unroll
        for (int ni = 0; ni < 2; ni++) {
            int col = bn * 256 + qn * 128 + wc * 32 + ni * 16 + cl;
            bv[qn][ni] = (col < Nvalid) ? bias[col] : 0.f;
        }

    f32x4 acc[2][2][4][2] = {};

#define ABASE(va) (A + (size_t)((bm0 + (va) / KTILES) * 256) * K)
#define KKOF(va)  (((va) % KTILES) * 64)
#define STAGEA(va, half) do { \
        const __hip_bfloat16* gg = ABASE(va) + (size_t)(half) * 128 * K + KKOF(va); \
        char* dd = lds + ((va) & 1) * 65536 + (half) * 16384 + ldsw; \
        gload_lds16(gg + arow0, dd); \
        gload_lds16(gg + arow1, dd + 8192); } while (0)
#define STAGEB(va, half) do { \
        const __hip_bfloat16* gg = Bbase + (size_t)(half) * 128 * K + KKOF(va); \
        char* dd = lds + ((va) & 1) * 65536 + 32768 + (half) * 16384 + ldsw; \
        gload_lds16(gg + arow0, dd); \
        gload_lds16(gg + arow1, dd + 8192); } while (0)

#define MFMA_Q(qm, qn, AF, BF) do { \
        _Pragma("unroll") \
        for (int mi = 0; mi < 4; mi++) \
            _Pragma("unroll") \
            for (int ni = 0; ni < 2; ni++) { \
                acc[qm][qn][mi][ni] = __builtin_amdgcn_mfma_f32_16x16x32_bf16(AF[mi][0], BF[ni][0], acc[qm][qn][mi][ni], 0, 0, 0); \
                acc[qm][qn][mi][ni] = __builtin_amdgcn_mfma_f32_16x16x32_bf16(AF[mi][1], BF[ni][1], acc[qm][qn][mi][ni], 0, 0, 0); \
            } } while (0)

    // quadrant write + acc reset (used in the last K-tile of each output tile)
#define WRQ(qm, qn) do { \
        int bmw = bm0 + v / KTILES; \
        _Pragma("unroll") \
        for (int mi = 0; mi < 4; mi++) \
            _Pragma("unroll") \
            for (int ni = 0; ni < 2; ni++) { \
                int col = bn * 256 + (qn) * 128 + wc * 32 + ni * 16 + cl; \
                if (col < Nvalid) { \
                    _Pragma("unroll") \
                    for (int j = 0; j < 4; j++) { \
                        int row = bmw * 256 + (qm) * 128 + wr * 64 + mi * 16 + rq * 4 + j; \
                        C[(size_t)row * ldc + col] = acc[qm][qn][mi][ni][j] + bv[qn][ni]; \
                    } \
                } \
                acc[qm][qn][mi][ni] = (f32x4){0.f, 0.f, 0.f, 0.f}; \
            } } while (0)

#define BAR() __builtin_amdgcn_s_barrier()

    // ---- prologue: v0 (A0,B0,B1,A1), v1 (A0,B0,B1); confirm v0, keep 6 in flight
    STAGEA(0, 0); STAGEB(0, 0); STAGEB(0, 1); STAGEA(0, 1);
    STAGEA(1, 0); STAGEB(1, 0); STAGEB(1, 1);
    asm volatile("s_waitcnt vmcnt(6)" ::: "memory");
    BAR();

    short8 af0[4][2], af1[4][2], bf0[2][2], bf1[2][2];
    for (int v = 0; v < VTOT; ++v) {
        int d = (v & 1) * 65536;
        bool last = ((v % KTILES) == KTILES - 1);

        // ---- Phase 1: read af0 + bf0; stage A1(v+1); MFMA Q(0,0)
        #pragma unroll
        for (int mi = 0; mi < 4; mi++) {
            af0[mi][0] = *(const short8*)(lds + d + aoff + mi * 2048 + rc0);
            af0[mi][1] = *(const short8*)(lds + d + aoff + mi * 2048 + rc1);
        }
        #pragma unroll
        for (int ni = 0; ni < 2; ni++) {
            bf0[ni][0] = *(const short8*)(lds + d + boff + ni * 2048 + rc0);
            bf0[ni][1] = *(const short8*)(lds + d + boff + ni * 2048 + rc1);
        }
        if (v + 1 < VTOT) STAGEA(v + 1, 1);
        BAR();
        __builtin_amdgcn_s_setprio(1);
        MFMA_Q(0, 0, af0, bf0);
        __builtin_amdgcn_s_setprio(0);
        if (last) WRQ(0, 0);
        BAR();

        // ---- Phase 2: read bf1; stage A0(v+2); MFMA Q(0,1)
        #pragma unroll
        for (int ni = 0; ni < 2; ni++) {
            bf1[ni][0] = *(const short8*)(lds + d + boff + 16384 + ni * 2048 + rc0);
            bf1[ni][1] = *(const short8*)(lds + d + boff + 16384 + ni * 2048 + rc1);
        }
        if (v + 2 < VTOT) STAGEA(v + 2, 0);
        BAR();
        __builtin_amdgcn_s_setprio(1);
        MFMA_Q(0, 1, af0, bf1);
        __builtin_amdgcn_s_setprio(0);
        if (last) WRQ(0, 1);
        BAR();

        // ---- Phase 3: read af1; stage B0(v+2); MFMA Q(1,1)
        #pragma unroll
        for (int mi = 0; mi < 4; mi++) {
            af1[mi][0] = *(const short8*)(lds + d + 16384 + aoff + mi * 2048 + rc0);
            af1[mi][1] = *(const short8*)(lds + d + 16384 + aoff + mi * 2048 + rc1);
        }
        if (v + 2 < VTOT) STAGEB(v + 2, 0);
        BAR();
        __builtin_amdgcn_s_setprio(1);
        MFMA_Q(1, 1, af1, bf1);
        __builtin_amdgcn_s_setprio(0);
        if (last) WRQ(1, 1);
        BAR();

        // ---- Phase 4: stage B1(v+2); counted vmcnt; MFMA Q(1,0)
        if (v + 2 < VTOT) STAGEB(v + 2, 1);
        if (v < VTOT - 2) asm volatile("s_waitcnt vmcnt(6)" ::: "memory");
        else              asm volatile("s_waitcnt vmcnt(0)" ::: "memory");
        BAR();
        __builtin_amdgcn_s_setprio(1);
        MFMA_Q(1, 0, af1, bf0);
        __builtin_amdgcn_s_setprio(0);
        if (last) WRQ(1, 0);
        BAR();
    }
#undef STAGEA
#undef STAGEB
#undef MFMA_Q
#undef WRQ
#undef BAR
#undef ABASE
#undef KKOF
}

extern "C" void kernel_launch(void* const* d_in, const int* in_sizes, int n_in,
                              void* d_out, int out_size, void* d_ws, size_t ws_size,
                              hipStream_t stream) {
    const float* hidden = (const float*)d_in[0];
    const int*   span   = (const int*)d_in[1];
    const float* pe     = (const float*)d_in[2];
    const float* W1     = (const float*)d_in[3];
    const float* b1     = (const float*)d_in[4];
    const float* g1     = (const float*)d_in[5];
    const float* be1    = (const float*)d_in[6];
    const float* W2     = (const float*)d_in[7];
    const float* b2     = (const float*)d_in[8];
    const float* g2     = (const float*)d_in[9];
    const float* be2    = (const float*)d_in[10];
    const float* Wdec   = (const float*)d_in[11];
    const float* dbias  = (const float*)d_in[12];
    float* out = (float*)d_out;

    const int M = BSZ * SEQ;  // 2048
    char* ws = (char*)d_ws;
    size_t off = 0;
    int* fw = (int*)(ws + off);                 off += (size_t)M * 4;
    int* bw = (int*)(ws + off);                 off += (size_t)M * 4;
    __hip_bfloat16* Xb   = (__hip_bfloat16*)(ws + off); off += (size_t)M * 3 * HID * 2;
    __hip_bfloat16* W1t  = (__hip_bfloat16*)(ws + off); off += (size_t)HID * 3 * HID * 2;
    __hip_bfloat16* W2t  = (__hip_bfloat16*)(ws + off); off += (size_t)HID * HID * 2;
    __hip_bfloat16* Wdt  = (__hip_bfloat16*)(ws + off); off += (size_t)NPAD * HID * 2;
    float* Y             = (float*)(ws + off);          off += (size_t)M * HID * 4 * 2;  // 2 split-K parts
    __hip_bfloat16* mid  = (__hip_bfloat16*)(ws + off); off += (size_t)M * HID * 2;
    __hip_bfloat16* pre  = (__hip_bfloat16*)(ws + off); off += (size_t)M * HID * 2;
    float* Y2 = Y + (size_t)M * HID;

    // 1. span scans
    scan_kernel<<<BSZ, SEQ, 0, stream>>>(span, fw, bw);
    // 2. gather + mask -> X bf16
    build_x<<<M, 256, 0, stream>>>(hidden, span, pe, fw, bw, Xb);
    // 3. weight transposes (f32 -> bf16, B^T layout)
    transpose64<<<dim3(HID / 64, 3 * HID / 64), 256, 0, stream>>>(W1, W1t, 3 * HID, HID);
    transpose64<<<dim3(HID / 64, HID / 64), 256, 0, stream>>>(W2, W2t, HID, HID);
    transpose64<<<dim3(NPAD / 64, HID / 64), 256, 0, stream>>>(Wdec, Wdt, HID, VOC);
    // 4. GEMM1 (split-K x2): X[2048,2304] @ W1 -> Y,Y2
    gemm_splitk<<<dim3(HID / 128, M / 128, 2), 256, 0, stream>>>(Xb, W1t, Y, 3 * HID, 3 * HID / 2, HID, (size_t)M * HID);
    // 5. (Y+Y2)+bias, gelu, LN -> mid
    gelu_ln<<<M, 256, 0, stream>>>(Y, Y2, b1, g1, be1, mid);
    // 6. GEMM2 (split-K x2): mid @ W2 -> Y,Y2
    gemm_splitk<<<dim3(HID / 128, M / 128, 2), 256, 0, stream>>>(mid, W2t, Y, HID, HID / 2, HID, (size_t)M * HID);
    // 7. (Y+Y2)+bias, gelu, LN -> pre
    gelu_ln<<<M, 256, 0, stream>>>(Y, Y2, b2, g2, be2, pre);
    // 8. decoder GEMM: persistent 256^2 8-phase, grid 240, 4 tiles/block
    gemm256p<<<240, 512, 0, stream>>>(pre, Wdt, out, HID, VOC, dbias, VOC);
}

// Round 7
// 233.785 us; speedup vs baseline: 1.2976x; 1.0820x over previous
//
#include <hip/hip_runtime.h>
#include <hip/hip_bf16.h>

#define BSZ 4
#define SEQ 512
#define HID 768
#define VOC 30522
#define NPAD 30720   // 120*256

typedef __attribute__((ext_vector_type(8))) short short8;
typedef __attribute__((ext_vector_type(4))) float f32x4;

typedef const unsigned int __attribute__((address_space(1)))* gptr_t;
typedef unsigned int __attribute__((address_space(3)))* lptr_t;

__device__ __forceinline__ void gload_lds16(const void* g, void* l) {
    __builtin_amdgcn_global_load_lds((gptr_t)g, (lptr_t)l, 16, 0, 0);
}

// ---------------- span scans ----------------
__global__ __launch_bounds__(512) void scan_kernel(const int* __restrict__ span,
                                                   int* __restrict__ fw, int* __restrict__ bw) {
    int b = blockIdx.x;
    int j = threadIdx.x;
    __shared__ int sm[SEQ];
    __shared__ int sc[SEQ];
    int m = (span[b * SEQ + j] > -1) ? 1 : 0;
    sm[j] = m;
    __syncthreads();
    int prev = (j > 0) ? sm[j - 1] : 0;
    int nxt  = (j < SEQ - 1) ? sm[j + 1] : 0;
    int cfw = (m && !prev && j > 0) ? (j - 1) : 0;
    int cbw = (m && !nxt && j < SEQ - 1) ? (j + 1) : (SEQ - 1);

    int v = cfw;
    sc[j] = v; __syncthreads();
    for (int off = 1; off < SEQ; off <<= 1) {
        int o = (j >= off) ? sc[j - off] : 0;
        __syncthreads();
        v = max(v, o);
        sc[j] = v; __syncthreads();
    }
    fw[b * SEQ + j] = v;

    v = cbw;
    sc[j] = v; __syncthreads();
    for (int off = 1; off < SEQ; off <<= 1) {
        int o = (j + off < SEQ) ? sc[j + off] : (SEQ - 1);
        __syncthreads();
        v = min(v, o);
        sc[j] = v; __syncthreads();
    }
    bw[b * SEQ + j] = v;
}

// ---------------- build X = [fw_h | bw_h | pe] * mask, bf16 (vectorized) ----------------
__global__ __launch_bounds__(384) void build_x(const float* __restrict__ h,
                                               const int* __restrict__ span,
                                               const float* __restrict__ pe,
                                               const int* __restrict__ fw,
                                               const int* __restrict__ bw,
                                               __hip_bfloat16* __restrict__ X) {
    int r = blockIdx.x;
    int b = r >> 9, s = r & (SEQ - 1);
    float mf = (span[r] > -1) ? 1.f : 0.f;
    int f = fw[r], w = bw[r];
    const float* hf = h + ((size_t)b * SEQ + f) * HID;
    const float* hb = h + ((size_t)b * SEQ + w) * HID;
    const float* pp = pe + (size_t)s * HID;
    __hip_bfloat16* xr = X + (size_t)r * (3 * HID);
    int c = threadIdx.x * 2;   // 0..766
    #pragma unroll
    for (int seg = 0; seg < 3; seg++) {
        const float* src = (seg == 0) ? hf : (seg == 1) ? hb : pp;
        float2 v = *(const float2*)&src[c];
        __hip_bfloat16 lo = __float2bfloat16(v.x * mf);
        __hip_bfloat16 hi = __float2bfloat16(v.y * mf);
        unsigned int pk = ((unsigned int)*(unsigned short*)&hi << 16) | *(unsigned short*)&lo;
        *(unsigned int*)&xr[seg * HID + c] = pk;
    }
}

// ---------------- merged transpose + f32->bf16 for W1, W2, Wdec ----------------
// Wt[n][k] = W[k][n], 64x64 tiles, packed-uint stores. One launch for all three.
#define T1_TILES (12 * 36)     // W1: N=768 (12) x K=2304 (36)
#define T2_TILES (12 * 12)     // W2: 768 x 768
#define TD_TILES (480 * 12)    // Wdec: N=30720 (480) x K=768 (12)
__global__ __launch_bounds__(256) void transpose_all(const float* __restrict__ W1, __hip_bfloat16* __restrict__ W1t,
                                                     const float* __restrict__ W2, __hip_bfloat16* __restrict__ W2t,
                                                     const float* __restrict__ Wd, __hip_bfloat16* __restrict__ Wdt) {
    int flat = blockIdx.x;
    const float* W; __hip_bfloat16* Wt; int K, N, tx_tiles, idx;
    if (flat < T1_TILES)                { W = W1; Wt = W1t; K = 3 * HID; N = HID; tx_tiles = 12;  idx = flat; }
    else if (flat < T1_TILES + T2_TILES){ W = W2; Wt = W2t; K = HID;     N = HID; tx_tiles = 12;  idx = flat - T1_TILES; }
    else                                { W = Wd; Wt = Wdt; K = HID;     N = VOC; tx_tiles = 480; idx = flat - T1_TILES - T2_TILES; }
    int n0 = (idx % tx_tiles) * 64, k0 = (idx / tx_tiles) * 64;

    __shared__ float t[64][67];
    int tx = threadIdx.x & 31, ty = threadIdx.x >> 5;
    #pragma unroll
    for (int i = 0; i < 64; i += 8) {
        #pragma unroll
        for (int jx = 0; jx < 64; jx += 32) {
            int k = k0 + ty + i, n = n0 + tx + jx;
            t[ty + i][tx + jx] = (n < N) ? W[(size_t)k * N + n] : 0.f;
        }
    }
    __syncthreads();
    #pragma unroll
    for (int i = 0; i < 8; i++) {
        int nn = ty + i * 8;
        int n = n0 + nn;
        float a = t[tx * 2][nn], b = t[tx * 2 + 1][nn];
        __hip_bfloat16 ba = __float2bfloat16(a), bb = __float2bfloat16(b);
        unsigned int pk = ((unsigned int)*(unsigned short*)&bb << 16) | *(unsigned short*)&ba;
        *(unsigned int*)&Wt[(size_t)n * K + k0 + tx * 2] = pk;
    }
}

// ---------------- sum(P split-K parts)+bias, exact gelu, layernorm -> bf16 ----------------
template<int P>
__global__ __launch_bounds__(256) void gelu_ln(const float* __restrict__ Y, size_t ystride,
                                               const float* __restrict__ bias,
                                               const float* __restrict__ g,
                                               const float* __restrict__ be,
                                               __hip_bfloat16* __restrict__ out) {
    int r = blockIdx.x;
    float z[3];
    float s1 = 0.f, s2 = 0.f;
    #pragma unroll
    for (int i = 0; i < 3; i++) {
        int c = threadIdx.x + i * 256;
        float x = bias[c];
        #pragma unroll
        for (int p = 0; p < P; p++)
            x += Y[p * ystride + (size_t)r * HID + c];
        float zz = 0.5f * x * (1.f + erff(x * 0.70710678118654752f));
        z[i] = zz; s1 += zz; s2 += zz * zz;
    }
    #pragma unroll
    for (int off = 32; off; off >>= 1) {
        s1 += __shfl_down(s1, off);
        s2 += __shfl_down(s2, off);
    }
    __shared__ float p1[4], p2[4];
    int w = threadIdx.x >> 6, lane = threadIdx.x & 63;
    if (lane == 0) { p1[w] = s1; p2[w] = s2; }
    __syncthreads();
    s1 = p1[0] + p1[1] + p1[2] + p1[3];
    s2 = p2[0] + p2[1] + p2[2] + p2[3];
    float mu = s1 * (1.f / HID);
    float var = s2 * (1.f / HID) - mu * mu;
    float rs = rsqrtf(var + 1e-12f);
    __hip_bfloat16* o = out + (size_t)r * HID;
    #pragma unroll
    for (int i = 0; i < 3; i++) {
        int c = threadIdx.x + i * 256;
        o[c] = __float2bfloat16((z[i] - mu) * rs * g[c] + be[c]);
    }
}

// ---------------- 128x128 MFMA GEMM with blockIdx.z split-K ----------------
__global__ __launch_bounds__(256) void gemm_splitk(const __hip_bfloat16* __restrict__ A,
                                                   const __hip_bfloat16* __restrict__ Bt,
                                                   float* __restrict__ C,
                                                   int lda, int Klen, int ldc, size_t cstride) {
    __shared__ __hip_bfloat16 As[128 * 64];
    __shared__ __hip_bfloat16 Bs[128 * 64];
    int bx = blockIdx.x;
    int by = blockIdx.y;
    int koff = blockIdx.z * Klen;
    float* Cz = C + (size_t)blockIdx.z * cstride;
    int t = threadIdx.x;
    int lane = t & 63, w = t >> 6;
    int wm = w >> 1, wn = w & 1;

    const __hip_bfloat16* Ab = A + (size_t)(by * 128) * lda + koff;
    const __hip_bfloat16* Bb = Bt + (size_t)(bx * 128) * lda + koff;

    f32x4 acc[4][4] = {};

    for (int k0 = 0; k0 < Klen; k0 += 64) {
        #pragma unroll
        for (int i = 0; i < 4; i++) {
            int c = i * 256 + t;
            int row = c >> 3, col = (c & 7) * 8;
            gload_lds16(Ab + (size_t)row * lda + k0 + col, (char*)As + c * 16);
            gload_lds16(Bb + (size_t)row * lda + k0 + col, (char*)Bs + c * 16);
        }
        __syncthreads();
        #pragma unroll
        for (int kk = 0; kk < 64; kk += 32) {
            short8 a[4], b[4];
            int col = kk + (lane >> 4) * 8;
            #pragma unroll
            for (int mi = 0; mi < 4; mi++) {
                int row = wm * 64 + mi * 16 + (lane & 15);
                a[mi] = *(const short8*)&As[row * 64 + col];
            }
            #pragma unroll
            for (int ni = 0; ni < 4; ni++) {
                int row = wn * 64 + ni * 16 + (lane & 15);
                b[ni] = *(const short8*)&Bs[row * 64 + col];
            }
            #pragma unroll
            for (int mi = 0; mi < 4; mi++)
                #pragma unroll
                for (int ni = 0; ni < 4; ni++)
                    acc[mi][ni] = __builtin_amdgcn_mfma_f32_16x16x32_bf16(a[mi], b[ni], acc[mi][ni], 0, 0, 0);
        }
        __syncthreads();
    }

    int rq = lane >> 4, cl = lane & 15;
    #pragma unroll
    for (int mi = 0; mi < 4; mi++) {
        #pragma unroll
        for (int ni = 0; ni < 4; ni++) {
            int col = bx * 128 + wn * 64 + ni * 16 + cl;
            #pragma unroll
            for (int j = 0; j < 4; j++) {
                int row = by * 128 + wm * 64 + mi * 16 + rq * 4 + j;
                Cz[(size_t)row * ldc + col] = acc[mi][ni][j];
            }
        }
    }
}

// ---------------- persistent 256x256 8-phase decoder GEMM (frozen from R6) ----------------
#define KTILES 12
#define TPB 4
#define VTOT (KTILES * TPB)
__global__ __launch_bounds__(512, 2) void gemm256p(const __hip_bfloat16* __restrict__ A,
                                                   const __hip_bfloat16* __restrict__ Bt,
                                                   float* __restrict__ C,
                                                   int K, int Nvalid,
                                                   const float* __restrict__ bias, int ldc) {
    __shared__ char lds[131072];
    int h = blockIdx.x;
    int chunk = gridDim.x >> 3;               // 30
    int l = (h & 7) * chunk + (h >> 3);
    int bn = l >> 1;
    int bm0 = (l & 1) * 4;

    int tid = threadIdx.x;
    int lane = tid & 63;
    int w = tid >> 6;
    int wr = w >> 2, wc = w & 3;

    // staging precompute
    int r0 = tid >> 3;
    int swz8 = (((tid & 7) ^ (r0 & 7)) << 3);
    const __hip_bfloat16* Bbase = Bt + (size_t)(bn * 256) * K;
    size_t arow0 = (size_t)r0 * K + swz8;
    size_t arow1 = arow0 + (size_t)64 * K;
    int ldsw = tid * 16;

    // frag read precompute (swizzled)
    int rxor = (lane & 7) << 4;
    int rcol = ((lane >> 4) & 3) * 16;
    int rc0 = (0 + rcol) ^ rxor;
    int rc1 = (64 + rcol) ^ rxor;
    int aoff = (wr * 64 + (lane & 15)) * 128;
    int boff = 32768 + (wc * 32 + (lane & 15)) * 128;

    // hoist bias: col depends on (qn,ni) only
    int rq = lane >> 4, cl = lane & 15;
    float bv[2][2];
    #pragma unroll
    for (int qn = 0; qn < 2; qn++)
        #pragma unroll
        for (int ni = 0; ni < 2; ni++) {
            int col = bn * 256 + qn * 128 + wc * 32 + ni * 16 + cl;
            bv[qn][ni] = (col < Nvalid) ? bias[col] : 0.f;
        }

    f32x4 acc[2][2][4][2] = {};

#define ABASE(va) (A + (size_t)((bm0 + (va) / KTILES) * 256) * K)
#define KKOF(va)  (((va) % KTILES) * 64)
#define STAGEA(va, half) do { \
        const __hip_bfloat16* gg = ABASE(va) + (size_t)(half) * 128 * K + KKOF(va); \
        char* dd = lds + ((va) & 1) * 65536 + (half) * 16384 + ldsw; \
        gload_lds16(gg + arow0, dd); \
        gload_lds16(gg + arow1, dd + 8192); } while (0)
#define STAGEB(va, half) do { \
        const __hip_bfloat16* gg = Bbase + (size_t)(half) * 128 * K + KKOF(va); \
        char* dd = lds + ((va) & 1) * 65536 + 32768 + (half) * 16384 + ldsw; \
        gload_lds16(gg + arow0, dd); \
        gload_lds16(gg + arow1, dd + 8192); } while (0)

#define MFMA_Q(qm, qn, AF, BF) do { \
        _Pragma("unroll") \
        for (int mi = 0; mi < 4; mi++) \
            _Pragma("unroll") \
            for (int ni = 0; ni < 2; ni++) { \
                acc[qm][qn][mi][ni] = __builtin_amdgcn_mfma_f32_16x16x32_bf16(AF[mi][0], BF[ni][0], acc[qm][qn][mi][ni], 0, 0, 0); \
                acc[qm][qn][mi][ni] = __builtin_amdgcn_mfma_f32_16x16x32_bf16(AF[mi][1], BF[ni][1], acc[qm][qn][mi][ni], 0, 0, 0); \
            } } while (0)

#define WRQ(qm, qn) do { \
        int bmw = bm0 + v / KTILES; \
        _Pragma("unroll") \
        for (int mi = 0; mi < 4; mi++) \
            _Pragma("unroll") \
            for (int ni = 0; ni < 2; ni++) { \
                int col = bn * 256 + (qn) * 128 + wc * 32 + ni * 16 + cl; \
                if (col < Nvalid) { \
                    _Pragma("unroll") \
                    for (int j = 0; j < 4; j++) { \
                        int row = bmw * 256 + (qm) * 128 + wr * 64 + mi * 16 + rq * 4 + j; \
                        C[(size_t)row * ldc + col] = acc[qm][qn][mi][ni][j] + bv[qn][ni]; \
                    } \
                } \
                acc[qm][qn][mi][ni] = (f32x4){0.f, 0.f, 0.f, 0.f}; \
            } } while (0)

#define BAR() __builtin_amdgcn_s_barrier()

    STAGEA(0, 0); STAGEB(0, 0); STAGEB(0, 1); STAGEA(0, 1);
    STAGEA(1, 0); STAGEB(1, 0); STAGEB(1, 1);
    asm volatile("s_waitcnt vmcnt(6)" ::: "memory");
    BAR();

    short8 af0[4][2], af1[4][2], bf0[2][2], bf1[2][2];
    for (int v = 0; v < VTOT; ++v) {
        int d = (v & 1) * 65536;
        bool last = ((v % KTILES) == KTILES - 1);

        // Phase 1
        #pragma unroll
        for (int mi = 0; mi < 4; mi++) {
            af0[mi][0] = *(const short8*)(lds + d + aoff + mi * 2048 + rc0);
            af0[mi][1] = *(const short8*)(lds + d + aoff + mi * 2048 + rc1);
        }
        #pragma unroll
        for (int ni = 0; ni < 2; ni++) {
            bf0[ni][0] = *(const short8*)(lds + d + boff + ni * 2048 + rc0);
            bf0[ni][1] = *(const short8*)(lds + d + boff + ni * 2048 + rc1);
        }
        if (v + 1 < VTOT) STAGEA(v + 1, 1);
        BAR();
        __builtin_amdgcn_s_setprio(1);
        MFMA_Q(0, 0, af0, bf0);
        __builtin_amdgcn_s_setprio(0);
        if (last) WRQ(0, 0);
        BAR();

        // Phase 2
        #pragma unroll
        for (int ni = 0; ni < 2; ni++) {
            bf1[ni][0] = *(const short8*)(lds + d + boff + 16384 + ni * 2048 + rc0);
            bf1[ni][1] = *(const short8*)(lds + d + boff + 16384 + ni * 2048 + rc1);
        }
        if (v + 2 < VTOT) STAGEA(v + 2, 0);
        BAR();
        __builtin_amdgcn_s_setprio(1);
        MFMA_Q(0, 1, af0, bf1);
        __builtin_amdgcn_s_setprio(0);
        if (last) WRQ(0, 1);
        BAR();

        // Phase 3
        #pragma unroll
        for (int mi = 0; mi < 4; mi++) {
            af1[mi][0] = *(const short8*)(lds + d + 16384 + aoff + mi * 2048 + rc0);
            af1[mi][1] = *(const short8*)(lds + d + 16384 + aoff + mi * 2048 + rc1);
        }
        if (v + 2 < VTOT) STAGEB(v + 2, 0);
        BAR();
        __builtin_amdgcn_s_setprio(1);
        MFMA_Q(1, 1, af1, bf1);
        __builtin_amdgcn_s_setprio(0);
        if (last) WRQ(1, 1);
        BAR();

        // Phase 4
        if (v + 2 < VTOT) STAGEB(v + 2, 1);
        if (v < VTOT - 2) asm volatile("s_waitcnt vmcnt(6)" ::: "memory");
        else              asm volatile("s_waitcnt vmcnt(0)" ::: "memory");
        BAR();
        __builtin_amdgcn_s_setprio(1);
        MFMA_Q(1, 0, af1, bf0);
        __builtin_amdgcn_s_setprio(0);
        if (last) WRQ(1, 0);
        BAR();
    }
#undef STAGEA
#undef STAGEB
#undef MFMA_Q
#undef WRQ
#undef BAR
#undef ABASE
#undef KKOF
}

extern "C" void kernel_launch(void* const* d_in, const int* in_sizes, int n_in,
                              void* d_out, int out_size, void* d_ws, size_t ws_size,
                              hipStream_t stream) {
    const float* hidden = (const float*)d_in[0];
    const int*   span   = (const int*)d_in[1];
    const float* pe     = (const float*)d_in[2];
    const float* W1     = (const float*)d_in[3];
    const float* b1     = (const float*)d_in[4];
    const float* g1     = (const float*)d_in[5];
    const float* be1    = (const float*)d_in[6];
    const float* W2     = (const float*)d_in[7];
    const float* b2     = (const float*)d_in[8];
    const float* g2     = (const float*)d_in[9];
    const float* be2    = (const float*)d_in[10];
    const float* Wdec   = (const float*)d_in[11];
    const float* dbias  = (const float*)d_in[12];
    float* out = (float*)d_out;

    const int M = BSZ * SEQ;  // 2048
    char* ws = (char*)d_ws;
    size_t off = 0;
    int* fw = (int*)(ws + off);                 off += (size_t)M * 4;
    int* bw = (int*)(ws + off);                 off += (size_t)M * 4;
    __hip_bfloat16* Xb   = (__hip_bfloat16*)(ws + off); off += (size_t)M * 3 * HID * 2;
    __hip_bfloat16* W1t  = (__hip_bfloat16*)(ws + off); off += (size_t)HID * 3 * HID * 2;
    __hip_bfloat16* W2t  = (__hip_bfloat16*)(ws + off); off += (size_t)HID * HID * 2;
    __hip_bfloat16* Wdt  = (__hip_bfloat16*)(ws + off); off += (size_t)NPAD * HID * 2;
    float* Y             = (float*)(ws + off);          off += (size_t)M * HID * 4 * 4;  // 4 split-K parts
    __hip_bfloat16* mid  = (__hip_bfloat16*)(ws + off); off += (size_t)M * HID * 2;
    __hip_bfloat16* pre  = (__hip_bfloat16*)(ws + off); off += (size_t)M * HID * 2;
    size_t ystride = (size_t)M * HID;

    // 1. span scans
    scan_kernel<<<BSZ, SEQ, 0, stream>>>(span, fw, bw);
    // 2. gather + mask -> X bf16 (vectorized)
    build_x<<<M, 384, 0, stream>>>(hidden, span, pe, fw, bw, Xb);
    // 3. all weight transposes in ONE launch
    transpose_all<<<T1_TILES + T2_TILES + TD_TILES, 256, 0, stream>>>(W1, W1t, W2, W2t, Wdec, Wdt);
    // 4. GEMM1 (split-K x4): X[2048,2304] @ W1 -> Y[0..3]
    gemm_splitk<<<dim3(HID / 128, M / 128, 4), 256, 0, stream>>>(Xb, W1t, Y, 3 * HID, 3 * HID / 4, HID, ystride);
    // 5. sum4+bias, gelu, LN -> mid
    gelu_ln<4><<<M, 256, 0, stream>>>(Y, ystride, b1, g1, be1, mid);
    // 6. GEMM2 (split-K x2): mid @ W2 -> Y[0..1]
    gemm_splitk<<<dim3(HID / 128, M / 128, 2), 256, 0, stream>>>(mid, W2t, Y, HID, HID / 2, HID, ystride);
    // 7. sum2+bias, gelu, LN -> pre
    gelu_ln<2><<<M, 256, 0, stream>>>(Y, ystride, b2, g2, be2, pre);
    // 8. decoder GEMM: persistent 256^2 8-phase, grid 240, 4 tiles/block
    gemm256p<<<240, 512, 0, stream>>>(pre, Wdt, out, HID, VOC, dbias, VOC);
}

// Round 8
// 217.993 us; speedup vs baseline: 1.3916x; 1.0724x over previous
//
#include <hip/hip_runtime.h>
#include <hip/hip_bf16.h>

#define BSZ 4
#define SEQ 512
#define HID 768
#define VOC 30522
#define NPAD 30720   // 120*256

typedef __attribute__((ext_vector_type(8))) short short8;
typedef __attribute__((ext_vector_type(4))) float f32x4;

typedef const unsigned int __attribute__((address_space(1)))* gptr_t;
typedef unsigned int __attribute__((address_space(3)))* lptr_t;

__device__ __forceinline__ void gload_lds16(const void* g, void* l) {
    __builtin_amdgcn_global_load_lds((gptr_t)g, (lptr_t)l, 16, 0, 0);
}

// ---------------- span scans ----------------
__global__ __launch_bounds__(512) void scan_kernel(const int* __restrict__ span,
                                                   int* __restrict__ fw, int* __restrict__ bw) {
    int b = blockIdx.x;
    int j = threadIdx.x;
    __shared__ int sm[SEQ];
    __shared__ int sc[SEQ];
    int m = (span[b * SEQ + j] > -1) ? 1 : 0;
    sm[j] = m;
    __syncthreads();
    int prev = (j > 0) ? sm[j - 1] : 0;
    int nxt  = (j < SEQ - 1) ? sm[j + 1] : 0;
    int cfw = (m && !prev && j > 0) ? (j - 1) : 0;
    int cbw = (m && !nxt && j < SEQ - 1) ? (j + 1) : (SEQ - 1);

    int v = cfw;
    sc[j] = v; __syncthreads();
    for (int off = 1; off < SEQ; off <<= 1) {
        int o = (j >= off) ? sc[j - off] : 0;
        __syncthreads();
        v = max(v, o);
        sc[j] = v; __syncthreads();
    }
    fw[b * SEQ + j] = v;

    v = cbw;
    sc[j] = v; __syncthreads();
    for (int off = 1; off < SEQ; off <<= 1) {
        int o = (j + off < SEQ) ? sc[j + off] : (SEQ - 1);
        __syncthreads();
        v = min(v, o);
        sc[j] = v; __syncthreads();
    }
    bw[b * SEQ + j] = v;
}

// ---------------- build X = [fw_h | bw_h | pe] * mask, bf16 (vectorized) ----------------
__global__ __launch_bounds__(384) void build_x(const float* __restrict__ h,
                                               const int* __restrict__ span,
                                               const float* __restrict__ pe,
                                               const int* __restrict__ fw,
                                               const int* __restrict__ bw,
                                               __hip_bfloat16* __restrict__ X) {
    int r = blockIdx.x;
    int b = r >> 9, s = r & (SEQ - 1);
    float mf = (span[r] > -1) ? 1.f : 0.f;
    int f = fw[r], w = bw[r];
    const float* hf = h + ((size_t)b * SEQ + f) * HID;
    const float* hb = h + ((size_t)b * SEQ + w) * HID;
    const float* pp = pe + (size_t)s * HID;
    __hip_bfloat16* xr = X + (size_t)r * (3 * HID);
    int c = threadIdx.x * 2;   // 0..766
    #pragma unroll
    for (int seg = 0; seg < 3; seg++) {
        const float* src = (seg == 0) ? hf : (seg == 1) ? hb : pp;
        float2 v = *(const float2*)&src[c];
        __hip_bfloat16 lo = __float2bfloat16(v.x * mf);
        __hip_bfloat16 hi = __float2bfloat16(v.y * mf);
        unsigned int pk = ((unsigned int)*(unsigned short*)&hi << 16) | *(unsigned short*)&lo;
        *(unsigned int*)&xr[seg * HID + c] = pk;
    }
}

// ---------------- merged transpose + f32->bf16 for W1, W2, Wdec ----------------
#define T1_TILES (12 * 36)
#define T2_TILES (12 * 12)
#define TD_TILES (480 * 12)
__global__ __launch_bounds__(256) void transpose_all(const float* __restrict__ W1, __hip_bfloat16* __restrict__ W1t,
                                                     const float* __restrict__ W2, __hip_bfloat16* __restrict__ W2t,
                                                     const float* __restrict__ Wd, __hip_bfloat16* __restrict__ Wdt) {
    int flat = blockIdx.x;
    const float* W; __hip_bfloat16* Wt; int K, N, tx_tiles, idx;
    if (flat < T1_TILES)                { W = W1; Wt = W1t; K = 3 * HID; N = HID; tx_tiles = 12;  idx = flat; }
    else if (flat < T1_TILES + T2_TILES){ W = W2; Wt = W2t; K = HID;     N = HID; tx_tiles = 12;  idx = flat - T1_TILES; }
    else                                { W = Wd; Wt = Wdt; K = HID;     N = VOC; tx_tiles = 480; idx = flat - T1_TILES - T2_TILES; }
    int n0 = (idx % tx_tiles) * 64, k0 = (idx / tx_tiles) * 64;

    __shared__ float t[64][67];
    int tx = threadIdx.x & 31, ty = threadIdx.x >> 5;
    #pragma unroll
    for (int i = 0; i < 64; i += 8) {
        #pragma unroll
        for (int jx = 0; jx < 64; jx += 32) {
            int k = k0 + ty + i, n = n0 + tx + jx;
            t[ty + i][tx + jx] = (n < N) ? W[(size_t)k * N + n] : 0.f;
        }
    }
    __syncthreads();
    #pragma unroll
    for (int i = 0; i < 8; i++) {
        int nn = ty + i * 8;
        int n = n0 + nn;
        float a = t[tx * 2][nn], b = t[tx * 2 + 1][nn];
        __hip_bfloat16 ba = __float2bfloat16(a), bb = __float2bfloat16(b);
        unsigned int pk = ((unsigned int)*(unsigned short*)&bb << 16) | *(unsigned short*)&ba;
        *(unsigned int*)&Wt[(size_t)n * K + k0 + tx * 2] = pk;
    }
}

// ---------------- sum(P split-K parts)+bias, exact gelu, layernorm -> bf16 ----------------
template<int P>
__global__ __launch_bounds__(256) void gelu_ln(const float* __restrict__ Y, size_t ystride,
                                               const float* __restrict__ bias,
                                               const float* __restrict__ g,
                                               const float* __restrict__ be,
                                               __hip_bfloat16* __restrict__ out) {
    int r = blockIdx.x;
    float z[3];
    float s1 = 0.f, s2 = 0.f;
    #pragma unroll
    for (int i = 0; i < 3; i++) {
        int c = threadIdx.x + i * 256;
        float x = bias[c];
        #pragma unroll
        for (int p = 0; p < P; p++)
            x += Y[p * ystride + (size_t)r * HID + c];
        float zz = 0.5f * x * (1.f + erff(x * 0.70710678118654752f));
        z[i] = zz; s1 += zz; s2 += zz * zz;
    }
    #pragma unroll
    for (int off = 32; off; off >>= 1) {
        s1 += __shfl_down(s1, off);
        s2 += __shfl_down(s2, off);
    }
    __shared__ float p1[4], p2[4];
    int w = threadIdx.x >> 6, lane = threadIdx.x & 63;
    if (lane == 0) { p1[w] = s1; p2[w] = s2; }
    __syncthreads();
    s1 = p1[0] + p1[1] + p1[2] + p1[3];
    s2 = p2[0] + p2[1] + p2[2] + p2[3];
    float mu = s1 * (1.f / HID);
    float var = s2 * (1.f / HID) - mu * mu;
    float rs = rsqrtf(var + 1e-12f);
    __hip_bfloat16* o = out + (size_t)r * HID;
    #pragma unroll
    for (int i = 0; i < 3; i++) {
        int c = threadIdx.x + i * 256;
        o[c] = __float2bfloat16((z[i] - mu) * rs * g[c] + be[c]);
    }
}

// ---------------- 128x128 MFMA GEMM with blockIdx.z split-K ----------------
__global__ __launch_bounds__(256) void gemm_splitk(const __hip_bfloat16* __restrict__ A,
                                                   const __hip_bfloat16* __restrict__ Bt,
                                                   float* __restrict__ C,
                                                   int lda, int Klen, int ldc, size_t cstride) {
    __shared__ __hip_bfloat16 As[128 * 64];
    __shared__ __hip_bfloat16 Bs[128 * 64];
    int bx = blockIdx.x;
    int by = blockIdx.y;
    int koff = blockIdx.z * Klen;
    float* Cz = C + (size_t)blockIdx.z * cstride;
    int t = threadIdx.x;
    int lane = t & 63, w = t >> 6;
    int wm = w >> 1, wn = w & 1;

    const __hip_bfloat16* Ab = A + (size_t)(by * 128) * lda + koff;
    const __hip_bfloat16* Bb = Bt + (size_t)(bx * 128) * lda + koff;

    f32x4 acc[4][4] = {};

    for (int k0 = 0; k0 < Klen; k0 += 64) {
        #pragma unroll
        for (int i = 0; i < 4; i++) {
            int c = i * 256 + t;
            int row = c >> 3, col = (c & 7) * 8;
            gload_lds16(Ab + (size_t)row * lda + k0 + col, (char*)As + c * 16);
            gload_lds16(Bb + (size_t)row * lda + k0 + col, (char*)Bs + c * 16);
        }
        __syncthreads();
        #pragma unroll
        for (int kk = 0; kk < 64; kk += 32) {
            short8 a[4], b[4];
            int col = kk + (lane >> 4) * 8;
            #pragma unroll
            for (int mi = 0; mi < 4; mi++) {
                int row = wm * 64 + mi * 16 + (lane & 15);
                a[mi] = *(const short8*)&As[row * 64 + col];
            }
            #pragma unroll
            for (int ni = 0; ni < 4; ni++) {
                int row = wn * 64 + ni * 16 + (lane & 15);
                b[ni] = *(const short8*)&Bs[row * 64 + col];
            }
            #pragma unroll
            for (int mi = 0; mi < 4; mi++)
                #pragma unroll
                for (int ni = 0; ni < 4; ni++)
                    acc[mi][ni] = __builtin_amdgcn_mfma_f32_16x16x32_bf16(a[mi], b[ni], acc[mi][ni], 0, 0, 0);
        }
        __syncthreads();
    }

    int rq = lane >> 4, cl = lane & 15;
    #pragma unroll
    for (int mi = 0; mi < 4; mi++) {
        #pragma unroll
        for (int ni = 0; ni < 4; ni++) {
            int col = bx * 128 + wn * 64 + ni * 16 + cl;
            #pragma unroll
            for (int j = 0; j < 4; j++) {
                int row = by * 128 + wm * 64 + mi * 16 + rq * 4 + j;
                Cz[(size_t)row * ldc + col] = acc[mi][ni][j];
            }
        }
    }
}

// ---------------- persistent 256x256 decoder GEMM, 2 merged phases / 2 barriers per K-tile ----------------
// Phase A: read ALL 24 frags of v (buf d) + stage A1(v+1)->e; BAR; 32 MFMA (Q00,Q01).
// Phase B: stage A0,B0,B1(v+2)->d; vmcnt(6); BAR; 32 MFMA (Q11,Q10).
// Ledger: vmcnt(6) at v.B leaves exactly v+2's 6 loads in flight -> A1(v+1)+older landed.
// Stage targets' last reads complete >=1 barrier + >=1000cy (MFMA cluster) before stage
// data can return from HBM; d.A1 (af1, consumed in MFMA-B) is never staged in phase B.
#define KTILES 12
#define TPB 4
#define VTOT (KTILES * TPB)
__global__ __launch_bounds__(512, 2) void gemm256p(const __hip_bfloat16* __restrict__ A,
                                                   const __hip_bfloat16* __restrict__ Bt,
                                                   float* __restrict__ C,
                                                   int K, int Nvalid,
                                                   const float* __restrict__ bias, int ldc) {
    __shared__ char lds[131072];
    int h = blockIdx.x;
    int chunk = gridDim.x >> 3;               // 30
    int l = (h & 7) * chunk + (h >> 3);
    int bn = l >> 1;
    int bm0 = (l & 1) * 4;

    int tid = threadIdx.x;
    int lane = tid & 63;
    int w = tid >> 6;
    int wr = w >> 2, wc = w & 3;

    // staging precompute
    int r0 = tid >> 3;
    int swz8 = (((tid & 7) ^ (r0 & 7)) << 3);
    const __hip_bfloat16* Bbase = Bt + (size_t)(bn * 256) * K;
    size_t arow0 = (size_t)r0 * K + swz8;
    size_t arow1 = arow0 + (size_t)64 * K;
    int ldsw = tid * 16;

    // frag read precompute (swizzled)
    int rxor = (lane & 7) << 4;
    int rcol = ((lane >> 4) & 3) * 16;
    int rc0 = (0 + rcol) ^ rxor;
    int rc1 = (64 + rcol) ^ rxor;
    int aoff = (wr * 64 + (lane & 15)) * 128;
    int boff = 32768 + (wc * 32 + (lane & 15)) * 128;

    // hoist bias
    int rq = lane >> 4, cl = lane & 15;
    float bv[2][2];
    #pragma unroll
    for (int qn = 0; qn < 2; qn++)
        #pragma unroll
        for (int ni = 0; ni < 2; ni++) {
            int col = bn * 256 + qn * 128 + wc * 32 + ni * 16 + cl;
            bv[qn][ni] = (col < Nvalid) ? bias[col] : 0.f;
        }

    f32x4 acc[2][2][4][2] = {};

#define ABASE(va) (A + (size_t)((bm0 + (va) / KTILES) * 256) * K)
#define KKOF(va)  (((va) % KTILES) * 64)
#define STAGEA(va, half) do { \
        const __hip_bfloat16* gg = ABASE(va) + (size_t)(half) * 128 * K + KKOF(va); \
        char* dd = lds + ((va) & 1) * 65536 + (half) * 16384 + ldsw; \
        gload_lds16(gg + arow0, dd); \
        gload_lds16(gg + arow1, dd + 8192); } while (0)
#define STAGEB(va, half) do { \
        const __hip_bfloat16* gg = Bbase + (size_t)(half) * 128 * K + KKOF(va); \
        char* dd = lds + ((va) & 1) * 65536 + 32768 + (half) * 16384 + ldsw; \
        gload_lds16(gg + arow0, dd); \
        gload_lds16(gg + arow1, dd + 8192); } while (0)

#define MFMA_Q(qm, qn, AF, BF) do { \
        _Pragma("unroll") \
        for (int mi = 0; mi < 4; mi++) \
            _Pragma("unroll") \
            for (int ni = 0; ni < 2; ni++) { \
                acc[qm][qn][mi][ni] = __builtin_amdgcn_mfma_f32_16x16x32_bf16(AF[mi][0], BF[ni][0], acc[qm][qn][mi][ni], 0, 0, 0); \
                acc[qm][qn][mi][ni] = __builtin_amdgcn_mfma_f32_16x16x32_bf16(AF[mi][1], BF[ni][1], acc[qm][qn][mi][ni], 0, 0, 0); \
            } } while (0)

#define WRQ(qm, qn) do { \
        int bmw = bm0 + v / KTILES; \
        _Pragma("unroll") \
        for (int mi = 0; mi < 4; mi++) \
            _Pragma("unroll") \
            for (int ni = 0; ni < 2; ni++) { \
                int col = bn * 256 + (qn) * 128 + wc * 32 + ni * 16 + cl; \
                if (col < Nvalid) { \
                    _Pragma("unroll") \
                    for (int j = 0; j < 4; j++) { \
                        int row = bmw * 256 + (qm) * 128 + wr * 64 + mi * 16 + rq * 4 + j; \
                        C[(size_t)row * ldc + col] = acc[qm][qn][mi][ni][j] + bv[qn][ni]; \
                    } \
                } \
                acc[qm][qn][mi][ni] = (f32x4){0.f, 0.f, 0.f, 0.f}; \
            } } while (0)

#define BAR() __builtin_amdgcn_s_barrier()

    // ---- prologue: v0 full (8 loads), v1 A0/B0/B1 (6 loads); confirm v0
    STAGEA(0, 0); STAGEB(0, 0); STAGEB(0, 1); STAGEA(0, 1);
    STAGEA(1, 0); STAGEB(1, 0); STAGEB(1, 1);
    asm volatile("s_waitcnt vmcnt(6)" ::: "memory");
    BAR();

    short8 af0[4][2], af1[4][2], bf0[2][2], bf1[2][2];
    for (int v = 0; v < VTOT; ++v) {
        int d = (v & 1) * 65536;
        bool last = ((v % KTILES) == KTILES - 1);

        // ---- Phase A: all reads of v; stage A1(v+1); BAR; MFMA Q00,Q01
        #pragma unroll
        for (int mi = 0; mi < 4; mi++) {
            af0[mi][0] = *(const short8*)(lds + d + aoff + mi * 2048 + rc0);
            af0[mi][1] = *(const short8*)(lds + d + aoff + mi * 2048 + rc1);
        }
        #pragma unroll
        for (int ni = 0; ni < 2; ni++) {
            bf0[ni][0] = *(const short8*)(lds + d + boff + ni * 2048 + rc0);
            bf0[ni][1] = *(const short8*)(lds + d + boff + ni * 2048 + rc1);
            bf1[ni][0] = *(const short8*)(lds + d + boff + 16384 + ni * 2048 + rc0);
            bf1[ni][1] = *(const short8*)(lds + d + boff + 16384 + ni * 2048 + rc1);
        }
        #pragma unroll
        for (int mi = 0; mi < 4; mi++) {
            af1[mi][0] = *(const short8*)(lds + d + 16384 + aoff + mi * 2048 + rc0);
            af1[mi][1] = *(const short8*)(lds + d + 16384 + aoff + mi * 2048 + rc1);
        }
        if (v + 1 < VTOT) STAGEA(v + 1, 1);
        BAR();
        __builtin_amdgcn_s_setprio(1);
        MFMA_Q(0, 0, af0, bf0);
        MFMA_Q(0, 1, af0, bf1);
        __builtin_amdgcn_s_setprio(0);
        if (last) { WRQ(0, 0); WRQ(0, 1); }

        // ---- Phase B: stage A0/B0/B1(v+2); counted vmcnt; BAR; MFMA Q11,Q10
        if (v + 2 < VTOT) { STAGEA(v + 2, 0); STAGEB(v + 2, 0); STAGEB(v + 2, 1); }
        if (v < VTOT - 2) asm volatile("s_waitcnt vmcnt(6)" ::: "memory");
        else              asm volatile("s_waitcnt vmcnt(0)" ::: "memory");
        BAR();
        __builtin_amdgcn_s_setprio(1);
        MFMA_Q(1, 1, af1, bf1);
        MFMA_Q(1, 0, af1, bf0);
        __builtin_amdgcn_s_setprio(0);
        if (last) { WRQ(1, 1); WRQ(1, 0); }
    }
#undef STAGEA
#undef STAGEB
#undef MFMA_Q
#undef WRQ
#undef BAR
#undef ABASE
#undef KKOF
}

extern "C" void kernel_launch(void* const* d_in, const int* in_sizes, int n_in,
                              void* d_out, int out_size, void* d_ws, size_t ws_size,
                              hipStream_t stream) {
    const float* hidden = (const float*)d_in[0];
    const int*   span   = (const int*)d_in[1];
    const float* pe     = (const float*)d_in[2];
    const float* W1     = (const float*)d_in[3];
    const float* b1     = (const float*)d_in[4];
    const float* g1     = (const float*)d_in[5];
    const float* be1    = (const float*)d_in[6];
    const float* W2     = (const float*)d_in[7];
    const float* b2     = (const float*)d_in[8];
    const float* g2     = (const float*)d_in[9];
    const float* be2    = (const float*)d_in[10];
    const float* Wdec   = (const float*)d_in[11];
    const float* dbias  = (const float*)d_in[12];
    float* out = (float*)d_out;

    const int M = BSZ * SEQ;  // 2048
    char* ws = (char*)d_ws;
    size_t off = 0;
    int* fw = (int*)(ws + off);                 off += (size_t)M * 4;
    int* bw = (int*)(ws + off);                 off += (size_t)M * 4;
    __hip_bfloat16* Xb   = (__hip_bfloat16*)(ws + off); off += (size_t)M * 3 * HID * 2;
    __hip_bfloat16* W1t  = (__hip_bfloat16*)(ws + off); off += (size_t)HID * 3 * HID * 2;
    __hip_bfloat16* W2t  = (__hip_bfloat16*)(ws + off); off += (size_t)HID * HID * 2;
    __hip_bfloat16* Wdt  = (__hip_bfloat16*)(ws + off); off += (size_t)NPAD * HID * 2;
    float* Y             = (float*)(ws + off);          off += (size_t)M * HID * 4 * 4;
    __hip_bfloat16* mid  = (__hip_bfloat16*)(ws + off); off += (size_t)M * HID * 2;
    __hip_bfloat16* pre  = (__hip_bfloat16*)(ws + off); off += (size_t)M * HID * 2;
    size_t ystride = (size_t)M * HID;

    // 1. span scans
    scan_kernel<<<BSZ, SEQ, 0, stream>>>(span, fw, bw);
    // 2. gather + mask -> X bf16 (vectorized)
    build_x<<<M, 384, 0, stream>>>(hidden, span, pe, fw, bw, Xb);
    // 3. all weight transposes in ONE launch
    transpose_all<<<T1_TILES + T2_TILES + TD_TILES, 256, 0, stream>>>(W1, W1t, W2, W2t, Wdec, Wdt);
    // 4. GEMM1 (split-K x4): X[2048,2304] @ W1 -> Y[0..3]
    gemm_splitk<<<dim3(HID / 128, M / 128, 4), 256, 0, stream>>>(Xb, W1t, Y, 3 * HID, 3 * HID / 4, HID, ystride);
    // 5. sum4+bias, gelu, LN -> mid
    gelu_ln<4><<<M, 256, 0, stream>>>(Y, ystride, b1, g1, be1, mid);
    // 6. GEMM2 (split-K x2): mid @ W2 -> Y[0..1]
    gemm_splitk<<<dim3(HID / 128, M / 128, 2), 256, 0, stream>>>(mid, W2t, Y, HID, HID / 2, HID, ystride);
    // 7. sum2+bias, gelu, LN -> pre
    gelu_ln<2><<<M, 256, 0, stream>>>(Y, ystride, b2, g2, be2, pre);
    // 8. decoder GEMM: persistent 256^2, 2-barrier merged phases, grid 240, 4 tiles/block
    gemm256p<<<240, 512, 0, stream>>>(pre, Wdt, out, HID, VOC, dbias, VOC);
}